// Round 6
// baseline (484.682 us; speedup 1.0000x reference)
//
#include <hip/hip_runtime.h>
#include <math.h>

// ContextCluster, fp32, MI355X gfx950 — round 6.
// K1: lane = output-channel. Per-lane conv weights live in 24 float4 VGPRs,
//     loaded ONCE per block (no scalar-K$ stream, no LDS weight traffic,
//     no per-region restage). x is wave-uniform per (k,px) -> ds_read_b128
//     broadcasts. Each block: one head, 4 regions; blk%8 = f2 -> per-XCD
//     x-strip stays L2-resident.
// K2: Wp chunk staged TRANSPOSED [k][oc] -> b128 weight broadcasts serve
//     4 FMAs each; disp streamed through a 16-deep per-lane register ring.

#define TPB 256

__global__ __launch_bounds__(TPB, 3)
void cc_cluster(const float* __restrict__ x,
                const float* __restrict__ Wf, const float* __restrict__ bf,
                const float* __restrict__ Wv, const float* __restrict__ bv,
                const float* __restrict__ salpha, const float* __restrict__ sbeta,
                float* __restrict__ disp)
{
    // buf: x tile [k][64] during conv (6144 floats), then fs[c][65] at 0,
    // vsh[c][65] at 2080 (4160 <= 6144). ~27.5 KB total LDS.
    __shared__ __align__(16) float buf[6144];
    __shared__ __align__(16) float centT[128];   // f centers transposed [c][m]
    __shared__ float vcent[132];                 // v centers [m][c]
    __shared__ float smask[256];                 // sims then masked sims [m][n]
    __shared__ float aggs[132];                  // agg [m][c]
    __shared__ float bsim[64];
    __shared__ int   bidx[64];
    __shared__ int   cnt[4];

    const int t     = threadIdx.x;
    const int lane  = t & 63;
    const int wid   = __builtin_amdgcn_readfirstlane(t >> 6);  // 0..3
    const int nbase = wid * 16;          // this wave's 16-pixel strip
    const int blk   = blockIdx.x;
    const int fq    = blk & 7;           // f2 (= XCD via blk%8)
    const int fh    = (blk >> 3) & 1;    // f1 half
    const int bb    = (blk >> 4) & 15;   // batch
    const int e     = blk >> 8;          // head

    const float alpha = salpha[0], beta = sbeta[0];

    // ---- per-lane weights: lane = oc (0..31 f, 32..63 v), loaded once ----
    const int oc = lane;
    const float* wrow = (oc < 32) ? (Wf + (size_t)(e*32 + oc)*96)
                                  : (Wv + (size_t)(e*32 + (oc - 32))*96);
    const float bias  = (oc < 32) ? bf[e*32 + oc] : bv[e*32 + (oc - 32)];
    float4 w_[24];
    #pragma unroll
    for (int i = 0; i < 24; ++i) w_[i] = ((const float4*)wrow)[i];

    // staging decode (fixed per thread): 6 float4 reads cover 96ch x 64px
    const int s_pq = t & 15;             // pixel-quad 0..15
    const int s_r  = s_pq >> 1;          // row in region 0..7
    const int s_h0 = (s_pq & 1) * 4;     // col start 0/4

    for (int ir = 0; ir < 4; ++ir) {
        const int f1   = fh*4 + ir;
        const int fold = f1*8 + fq;

        // ---- stage x region -> buf[k][64] (coalesced float4) ----
        const float* xb = x + (size_t)bb*96*4096 + (size_t)(f1*8)*64 + fq*8;
        #pragma unroll
        for (int i2 = 0; i2 < 6; ++i2) {
            int ch = i2*16 + (t >> 4);
            float4 v = *(const float4*)(xb + (size_t)ch*4096 + s_r*64 + s_h0);
            *(float4*)&buf[ch*64 + 4*s_pq] = v;
        }
        __syncthreads();                  // x tile ready

        // ---- conv: acc[16 px] per lane-channel; x via b128 broadcasts ----
        float acc[16];
        #pragma unroll
        for (int j = 0; j < 16; ++j) acc[j] = bias;
        #pragma unroll
        for (int kg = 0; kg < 24; ++kg) {
            const float4 wk = w_[kg];
            #pragma unroll
            for (int kk = 0; kk < 4; ++kk) {
                const float wv = (kk==0) ? wk.x : (kk==1) ? wk.y
                               : (kk==2) ? wk.z : wk.w;
                const int kb = (kg*4 + kk)*64 + nbase;
                #pragma unroll
                for (int q = 0; q < 4; ++q) {
                    const float4 xq = *(const float4*)&buf[kb + 4*q];
                    acc[4*q+0] = fmaf(wv, xq.x, acc[4*q+0]);
                    acc[4*q+1] = fmaf(wv, xq.y, acc[4*q+1]);
                    acc[4*q+2] = fmaf(wv, xq.z, acc[4*q+2]);
                    acc[4*q+3] = fmaf(wv, xq.w, acc[4*q+3]);
                }
            }
        }
        __syncthreads();                  // conv reads of buf done

        // ---- write f/v points: fs = buf[0..2080), vsh = buf[2080..4160) ----
        {
            float* dst = (oc < 32) ? &buf[oc*65] : &buf[2080 + (oc - 32)*65];
            #pragma unroll
            for (int j = 0; j < 16; ++j) dst[nbase + j] = acc[j];
        }
        if (t < 4) cnt[t] = 0;
        __syncthreads();

        // ---- P1: max-pool centers (t<128: f -> centT; t>=128: v -> vcent) ----
        {
            int tt = t & 127;
            int m = tt >> 5, c = tt & 31;
            int pw = m >> 1, ph = m & 1;
            const float* src = (t < 128) ? buf : (buf + 2080);
            float mx = -3.402823466e38f;
            #pragma unroll
            for (int a = 0; a < 4; ++a)
                #pragma unroll
                for (int b2 = 0; b2 < 4; ++b2) {
                    int n = (pw*4 + a)*8 + ph*4 + b2;
                    mx = fmaxf(mx, src[c*65 + n]);
                }
            if (t < 128) centT[c*4 + m]  = mx;
            else         vcent[m*33 + c] = mx;
        }
        __syncthreads();

        // ---- P2a: sims, all 256 threads: m = wave, n = lane ----
        {
            const int m = wid, n = lane;
            float d = 0.f, pn = 0.f, cn = 0.f;
            #pragma unroll
            for (int c = 0; c < 32; ++c) {
                float fv = buf[c*65 + n];
                float cm = centT[c*4 + m];
                d  = fmaf(cm, fv, d);
                pn = fmaf(fv, fv, pn);
                cn = fmaf(cm, cm, cn);
            }
            float ip = 1.f / fmaxf(sqrtf(pn), 1e-12f);
            float ic = 1.f / fmaxf(sqrtf(cn), 1e-12f);
            float z  = beta + alpha * (d * ic * ip);
            smask[m*64 + n] = 1.f / (1.f + expf(-z));
        }
        __syncthreads();

        // ---- P2b: argmax + mask (wave 0) ----
        if (t < 64) {
            int n = t;
            float s0 = smask[n], s1 = smask[64+n], s2 = smask[128+n], s3 = smask[192+n];
            int bi = 0; float bv2 = s0;            // first-max tie-break
            if (s1 > bv2) { bv2 = s1; bi = 1; }
            if (s2 > bv2) { bv2 = s2; bi = 2; }
            if (s3 > bv2) { bv2 = s3; bi = 3; }
            bidx[n] = bi; bsim[n] = bv2;
            smask[n]       = (bi==0) ? bv2 : 0.f;
            smask[64 + n]  = (bi==1) ? bv2 : 0.f;
            smask[128 + n] = (bi==2) ? bv2 : 0.f;
            smask[192 + n] = (bi==3) ? bv2 : 0.f;
            atomicAdd(&cnt[bi], 1);
        }
        __syncthreads();

        // ---- P4: aggregate points -> centers ----
        if (t < 128) {
            int m = t >> 5, c = t & 31;
            float s = 0.f;
            const float* sm = &smask[m*64];
            const float* vv = buf + 2080;
            #pragma unroll 8
            for (int n2 = 0; n2 < 64; ++n2)
                s = fmaf(vv[c*65 + n2], sm[n2], s);
            aggs[m*33 + c] = (s + vcent[m*33 + c]) / (float)(cnt[m] + 1);
        }
        __syncthreads();

        // ---- P5: dispatch -> disp[bb][e*32+c][fold][n] (coalesced) ----
        {
            float bs = bsim[lane];
            int   bi = bidx[lane];
            size_t obase = (size_t)bb*256*4096 + (size_t)(e*32)*4096
                         + (size_t)fold*64 + lane;
            #pragma unroll
            for (int j = 0; j < 8; ++j) {
                int c = wid*8 + j;
                disp[obase + (size_t)c*4096] = aggs[bi*33 + c] * bs;
            }
        }
        // staging of next region may overwrite buf only after all waves'
        // P4 reads — guaranteed by the pre-P5 barrier; P5 reads no buf.
    }
}

// K2: out[bb][o][w][h] = sum_c Wp[o][c] * disp[bb][c][fold][n] + bp[o]
// Wp chunk transposed in LDS [k][100] -> b128 broadcasts (1 per 4 FMA).
// disp: 16-deep per-lane register ring, 1 refill per 24 FMAs.
__global__ __launch_bounds__(TPB, 4)
void cc_proj(const float* __restrict__ disp, const float* __restrict__ Wp,
             const float* __restrict__ bp, float* __restrict__ out)
{
    __shared__ __align__(16) float wch[64*100];  // [k_local][oc], pad 100
    const int t    = threadIdx.x;
    const int lane = t & 63;
    const int wid  = __builtin_amdgcn_readfirstlane(t >> 6);  // 0..3
    const int fold = blockIdx.x & 63;
    const int bb   = blockIdx.x >> 6;
    const int f1   = fold >> 3, f2 = fold & 7;

    const float* dp = disp + (size_t)bb*256*4096 + (size_t)fold*64 + lane;

    float acc[24];
    #pragma unroll
    for (int j = 0; j < 24; ++j) acc[j] = bp[wid*24 + j];

    // 16-deep disp ring: xr[i] holds k = kc + kb*16 + i
    float xr[16];
    #pragma unroll
    for (int i = 0; i < 16; ++i) xr[i] = dp[(size_t)i*4096];

    for (int kc = 0; kc < 256; kc += 64) {
        if (kc) __syncthreads();          // prev chunk consumed
        // stage Wp[:, kc:kc+64] transposed: wch[k][oc]
        #pragma unroll
        for (int i2 = 0; i2 < 6; ++i2) {
            int oc2 = i2*16 + (t >> 4);   // 0..95
            int pq  = t & 15;
            float4 wq = *(const float4*)(Wp + (size_t)oc2*256 + kc + 4*pq);
            wch[(4*pq+0)*100 + oc2] = wq.x;
            wch[(4*pq+1)*100 + oc2] = wq.y;
            wch[(4*pq+2)*100 + oc2] = wq.z;
            wch[(4*pq+3)*100 + oc2] = wq.w;
        }
        __syncthreads();                  // chunk ready

        for (int kb = 0; kb < 4; ++kb) {
            #pragma unroll
            for (int i = 0; i < 16; ++i) {
                float xv = xr[i];
                int g = kc + kb*16 + i + 16;
                if (g > 255) g = 255;     // clamped harmless refill
                xr[i] = dp[(size_t)g*4096];
                const float* wb = &wch[(kb*16 + i)*100 + wid*24];
                #pragma unroll
                for (int jg = 0; jg < 6; ++jg) {
                    float4 w4 = *(const float4*)(wb + 4*jg);
                    acc[4*jg+0] = fmaf(w4.x, xv, acc[4*jg+0]);
                    acc[4*jg+1] = fmaf(w4.y, xv, acc[4*jg+1]);
                    acc[4*jg+2] = fmaf(w4.z, xv, acc[4*jg+2]);
                    acc[4*jg+3] = fmaf(w4.w, xv, acc[4*jg+3]);
                }
            }
        }
    }

    // out pixel: w = f1*8 + n/8, h = f2*8 + n%8
    size_t obase = (size_t)bb*96*4096 + (size_t)(f1*8 + (lane >> 3))*64
                 + f2*8 + (lane & 7);
    #pragma unroll
    for (int j = 0; j < 24; ++j)
        out[obase + (size_t)(wid*24 + j)*4096] = acc[j];
}

extern "C" void kernel_launch(void* const* d_in, const int* in_sizes, int n_in,
                              void* d_out, int out_size, void* d_ws, size_t ws_size,
                              hipStream_t stream) {
    (void)in_sizes; (void)n_in; (void)out_size; (void)ws_size;
    float* disp = (float*)d_ws;   // 16*256*4096 floats = 64 MiB
    cc_cluster<<<dim3(2048), dim3(TPB), 0, stream>>>(
        (const float*)d_in[0],  // x
        (const float*)d_in[1],  // Wf
        (const float*)d_in[2],  // bf
        (const float*)d_in[3],  // Wv
        (const float*)d_in[4],  // bv
        (const float*)d_in[7],  // sim_alpha
        (const float*)d_in[8],  // sim_beta
        disp);
    cc_proj<<<dim3(1024), dim3(TPB), 0, stream>>>(
        disp,
        (const float*)d_in[5],  // Wp
        (const float*)d_in[6],  // bp
        (float*)d_out);
}

// Round 7
// 311.397 us; speedup vs baseline: 1.5565x; 1.5565x over previous
//
#include <hip/hip_runtime.h>
#include <math.h>

// ContextCluster, fp32, MI355X gfx950 — round 7.
// K1: register-tiled GEMM conv (128ch x 128px per block, thread tile 8x8,
//     operands via LDS, K=96 in 3 chunks with register prefetch) + fused
//     cluster: after GEMM each wave independently handles one (head,region)
//     problem (ballot-based counts, no inter-wave phase barriers).
//     Block = (head-pair heg, batch bb, fold-pair fp). disp layout [ch][p''],
//     p'' = bb*4096 + fold*64 + n (region-major) for K2's GEMM.
// K2: register-tiled GEMM proj: C[96][p''] = Wp @ disp, thread tile 6x8.

#define TPB 256

__global__ __launch_bounds__(TPB, 2)
void cc_main(const float* __restrict__ x,
             const float* __restrict__ Wf, const float* __restrict__ bf,
             const float* __restrict__ Wv, const float* __restrict__ bv,
             const float* __restrict__ salpha, const float* __restrict__ sbeta,
             float* __restrict__ disp)
{
    // GEMM phase: Wt = smem[0..4096) [k][128ch], Xt = smem[4096..8192) [k][128px]
    // Cluster phase: fvbuf = smem[0..8320) [128ch][65]
    __shared__ __align__(16) float smem[8320];
    __shared__ float cfs[2][132], cvs[2][132], swb[2][256], aggs[2][132];

    const int t    = threadIdx.x;
    const int lane = t & 63;
    const int wid  = __builtin_amdgcn_readfirstlane(t >> 6);  // 0..3
    const int tc   = t >> 4;          // 0..15: ch-group (8 ch)
    const int tp   = t & 15;          // px-group (8 px, stride 16)
    const int blk  = blockIdx.x;
    const int heg  = blk >> 9;        // head-pair 0..3 (heads 2heg, 2heg+1)
    const int pxt  = blk & 511;       // px-tile; pxt%8 = XCD
    const int bb   = pxt >> 5;        // batch
    const int fp   = pxt & 31;        // fold-pair: folds 2fp, 2fp+1

    const float* xb = x + (size_t)bb*96*4096;

    // ---- accumulators, bias-init (same order as prior rounds) ----
    float acc[8][8];
    {
        const float* bsrc = (tc < 8) ? (bf + heg*64 + tc*8)
                                     : (bv + heg*64 + (tc-8)*8);
        float4 b0 = *(const float4*)bsrc;
        float4 b1 = *(const float4*)(bsrc + 4);
        #pragma unroll
        for (int i = 0; i < 8; ++i) {
            acc[0][i]=b0.x; acc[1][i]=b0.y; acc[2][i]=b0.z; acc[3][i]=b0.w;
            acc[4][i]=b1.x; acc[5][i]=b1.y; acc[6][i]=b1.z; acc[7][i]=b1.w;
        }
    }

    // ---- staging decode (t-constant) ----
    int xoff[4], xdst[4], wdst[4];
    const float* wptr[4];
    #pragma unroll
    for (int i = 0; i < 4; ++i) {
        int fl = i*256 + t;
        int kl = fl >> 5, sg = fl & 31;          // X: k-local, float4-col
        int region = sg >> 4, s4 = sg & 15;
        int fold = fp*2 + region;
        xoff[i] = kl*4096 + ((fold>>3)*8 + (s4>>1))*64 + (fold&7)*8 + (s4&1)*4;
        xdst[i] = 4096 + kl*128 + sg*4;
        int rr = fl >> 3, kq = fl & 7;           // W: ch-row, float4-k
        wptr[i] = ((rr < 64) ? (Wf + (size_t)(heg*64 + rr)*96)
                             : (Wv + (size_t)(heg*64 + rr - 64)*96)) + kq*4;
        wdst[i] = (kq*4)*128 + rr;
    }

    float4 pxr[4], pwr[4];
    // load chunk 0
    #pragma unroll
    for (int i = 0; i < 4; ++i) {
        pxr[i] = *(const float4*)(xb + xoff[i]);
        pwr[i] = *(const float4*)(wptr[i]);
    }
    // store chunk 0
    #pragma unroll
    for (int i = 0; i < 4; ++i) {
        *(float4*)&smem[xdst[i]] = pxr[i];
        smem[wdst[i]      ] = pwr[i].x;
        smem[wdst[i] + 128] = pwr[i].y;
        smem[wdst[i] + 256] = pwr[i].z;
        smem[wdst[i] + 384] = pwr[i].w;
    }
    __syncthreads();                  // chunk0 ready

    for (int kc = 0; ; ) {
        if (kc < 64) {                // prefetch next chunk into regs
            #pragma unroll
            for (int i = 0; i < 4; ++i) {
                pxr[i] = *(const float4*)(xb + (kc+32)*4096 + xoff[i]);
                pwr[i] = *(const float4*)(wptr[i] + kc + 32);
            }
        }
        // ---- GEMM on current chunk: 32 k, 64 FMA/thread/k ----
        #pragma unroll 4
        for (int k = 0; k < 32; ++k) {
            float4 wa = *(const float4*)&smem[k*128 + tc*8];
            float4 wb4 = *(const float4*)&smem[k*128 + tc*8 + 4];
            float xv[8];
            #pragma unroll
            for (int i = 0; i < 8; ++i) xv[i] = smem[4096 + k*128 + tp + 16*i];
            #pragma unroll
            for (int i = 0; i < 8; ++i) {
                acc[0][i] = fmaf(wa.x,  xv[i], acc[0][i]);
                acc[1][i] = fmaf(wa.y,  xv[i], acc[1][i]);
                acc[2][i] = fmaf(wa.z,  xv[i], acc[2][i]);
                acc[3][i] = fmaf(wa.w,  xv[i], acc[3][i]);
                acc[4][i] = fmaf(wb4.x, xv[i], acc[4][i]);
                acc[5][i] = fmaf(wb4.y, xv[i], acc[5][i]);
                acc[6][i] = fmaf(wb4.z, xv[i], acc[6][i]);
                acc[7][i] = fmaf(wb4.w, xv[i], acc[7][i]);
            }
        }
        if (kc == 64) break;
        __syncthreads();              // chunk consumed
        #pragma unroll
        for (int i = 0; i < 4; ++i) {
            *(float4*)&smem[xdst[i]] = pxr[i];
            smem[wdst[i]      ] = pwr[i].x;
            smem[wdst[i] + 128] = pwr[i].y;
            smem[wdst[i] + 256] = pwr[i].z;
            smem[wdst[i] + 384] = pwr[i].w;
        }
        __syncthreads();              // next chunk ready
        kc += 32;
    }

    // ---- cluster: 2 region passes; each active wave owns one (head,region) ----
    const float alpha = salpha[0], beta = sbeta[0];
    #pragma unroll 1
    for (int rg = 0; rg < 2; ++rg) {
        __syncthreads();              // prior smem use done
        // dump region rg: fvbuf[ch][n] (stride 65)
        #pragma unroll
        for (int j = 0; j < 8; ++j)
            #pragma unroll
            for (int i2 = 0; i2 < 4; ++i2)
                smem[(tc*8 + j)*65 + tp + 16*i2] = acc[j][i2 + rg*4];
        __syncthreads();

        if ((wid >> 1) == rg) {
            const int he = wid & 1, slot = he;
            const int fold = fp*2 + rg;
            // pool: lane -> (m = lane>>4, c0 = (lane&15)*2), 2 centers each
            {
                int m = lane >> 4, c0 = (lane & 15)*2;
                int pw = m >> 1, ph = m & 1;
                #pragma unroll
                for (int cc = 0; cc < 2; ++cc) {
                    int c = c0 + cc;
                    float mf = -3.402823466e38f, mv = -3.402823466e38f;
                    #pragma unroll
                    for (int a = 0; a < 4; ++a)
                        #pragma unroll
                        for (int b2 = 0; b2 < 4; ++b2) {
                            int n = (pw*4 + a)*8 + ph*4 + b2;
                            mf = fmaxf(mf, smem[(he*32 + c)*65 + n]);
                            mv = fmaxf(mv, smem[(64 + he*32 + c)*65 + n]);
                        }
                    cfs[slot][m*33 + c] = mf;
                    cvs[slot][m*33 + c] = mv;
                }
            }
            // sims (lane = n): dots vs 4 centers + norms
            float d0=0,d1=0,d2=0,d3=0,pn=0,cn0=0,cn1=0,cn2=0,cn3=0;
            #pragma unroll 8
            for (int c = 0; c < 32; ++c) {
                float fv = smem[(he*32 + c)*65 + lane];
                float m0 = cfs[slot][c], m1 = cfs[slot][33+c];
                float m2 = cfs[slot][66+c], m3 = cfs[slot][99+c];
                d0 = fmaf(m0, fv, d0); d1 = fmaf(m1, fv, d1);
                d2 = fmaf(m2, fv, d2); d3 = fmaf(m3, fv, d3);
                pn = fmaf(fv, fv, pn);
                cn0 = fmaf(m0, m0, cn0); cn1 = fmaf(m1, m1, cn1);
                cn2 = fmaf(m2, m2, cn2); cn3 = fmaf(m3, m3, cn3);
            }
            float ip = 1.f / fmaxf(sqrtf(pn), 1e-12f);
            float z0 = beta + alpha*(d0*(1.f/fmaxf(sqrtf(cn0),1e-12f))*ip);
            float z1 = beta + alpha*(d1*(1.f/fmaxf(sqrtf(cn1),1e-12f))*ip);
            float z2 = beta + alpha*(d2*(1.f/fmaxf(sqrtf(cn2),1e-12f))*ip);
            float z3 = beta + alpha*(d3*(1.f/fmaxf(sqrtf(cn3),1e-12f))*ip);
            float s0 = 1.f/(1.f + expf(-z0));
            float s1 = 1.f/(1.f + expf(-z1));
            float s2 = 1.f/(1.f + expf(-z2));
            float s3 = 1.f/(1.f + expf(-z3));
            int bi = 0; float bvv = s0;        // first-max tie-break
            if (s1 > bvv) { bvv = s1; bi = 1; }
            if (s2 > bvv) { bvv = s2; bi = 2; }
            if (s3 > bvv) { bvv = s3; bi = 3; }
            int cnt0 = __popcll(__ballot(bi == 0));
            int cnt1 = __popcll(__ballot(bi == 1));
            int cnt2 = __popcll(__ballot(bi == 2));
            int cnt3 = __popcll(__ballot(bi == 3));
            swb[slot][lane]       = (bi==0) ? bvv : 0.f;
            swb[slot][64 + lane]  = (bi==1) ? bvv : 0.f;
            swb[slot][128 + lane] = (bi==2) ? bvv : 0.f;
            swb[slot][192 + lane] = (bi==3) ? bvv : 0.f;
            // agg: 2 iters, lane -> (m = it*2 + lane>>5, c = lane&31)
            #pragma unroll
            for (int it = 0; it < 2; ++it) {
                int m = it*2 + (lane >> 5);
                int c = lane & 31;
                float s = 0.f;
                #pragma unroll 8
                for (int n2 = 0; n2 < 64; ++n2)
                    s = fmaf(smem[(64 + he*32 + c)*65 + n2],
                             swb[slot][m*64 + n2], s);
                int cm = (m==0) ? cnt0 : (m==1) ? cnt1 : (m==2) ? cnt2 : cnt3;
                aggs[slot][m*33 + c] = (s + cvs[slot][m*33 + c]) / (float)(cm + 1);
            }
            // dispatch -> disp[ch][p'']
            const int e32 = (heg*2 + he)*32;
            const size_t obase = (size_t)bb*4096 + (size_t)fold*64 + lane;
            #pragma unroll 4
            for (int c = 0; c < 32; ++c)
                disp[(size_t)(e32 + c)*65536 + obase] = aggs[slot][bi*33 + c] * bvv;
        }
    }
}

// K2: C[96][p''] = Wp[96][256] @ disp[256][p''] + bp; thread tile 6oc x 8px.
__global__ __launch_bounds__(TPB, 3)
void cc_proj(const float* __restrict__ disp, const float* __restrict__ Wp,
             const float* __restrict__ bp, float* __restrict__ out)
{
    __shared__ __align__(16) float wch[3200];    // [32k][100] (oc, pad 100)
    __shared__ __align__(16) float xch[4096];    // [32k][128px]
    const int t   = threadIdx.x;
    const int toc = t >> 4;           // 0..15: oc-group (6 oc)
    const int tp  = t & 15;           // px-group (8 px, stride 16)
    const int b   = blockIdx.x;
    // pxt such that (pxt>>1)%8 == b%8 (XCD matches K1's disp writer)
    const int pxt = (b >> 4)*16 + ((b & 7) << 1) + ((b >> 3) & 1);
    const int pxbase = pxt * 128;
    const int bb = pxbase >> 12;

    float acc[6][8];
    {
        float b0 = bp[toc*6+0], b1 = bp[toc*6+1], b2 = bp[toc*6+2];
        float b3 = bp[toc*6+3], b4 = bp[toc*6+4], b5 = bp[toc*6+5];
        #pragma unroll
        for (int i = 0; i < 8; ++i) {
            acc[0][i]=b0; acc[1][i]=b1; acc[2][i]=b2;
            acc[3][i]=b3; acc[4][i]=b4; acc[5][i]=b5;
        }
    }

    // staging decode
    int woffg[3], wdst[3], xoffg[4], xdst[4];
    #pragma unroll
    for (int i = 0; i < 3; ++i) {
        int fl = i*256 + t;
        int oc2 = fl >> 3, kq = fl & 7;
        woffg[i] = oc2*256 + kq*4;
        wdst[i]  = (kq*4)*100 + oc2;
    }
    #pragma unroll
    for (int i = 0; i < 4; ++i) {
        int fl = i*256 + t;
        int kl = fl >> 5, sg = fl & 31;
        xoffg[i] = kl*65536 + pxbase + sg*4;
        xdst[i]  = kl*128 + sg*4;
    }

    float4 pwr[3], pxr[4];
    #pragma unroll
    for (int i = 0; i < 3; ++i) pwr[i] = *(const float4*)(Wp + woffg[i]);
    #pragma unroll
    for (int i = 0; i < 4; ++i) pxr[i] = *(const float4*)(disp + xoffg[i]);
    #pragma unroll
    for (int i = 0; i < 3; ++i) {
        wch[wdst[i]      ] = pwr[i].x; wch[wdst[i] + 100] = pwr[i].y;
        wch[wdst[i] + 200] = pwr[i].z; wch[wdst[i] + 300] = pwr[i].w;
    }
    #pragma unroll
    for (int i = 0; i < 4; ++i) *(float4*)&xch[xdst[i]] = pxr[i];
    __syncthreads();

    for (int kc = 0; ; ) {
        if (kc < 224) {
            #pragma unroll
            for (int i = 0; i < 3; ++i)
                pwr[i] = *(const float4*)(Wp + woffg[i] + kc + 32);
            #pragma unroll
            for (int i = 0; i < 4; ++i)
                pxr[i] = *(const float4*)(disp + xoffg[i] + (size_t)(kc+32)*65536);
        }
        #pragma unroll 4
        for (int k = 0; k < 32; ++k) {
            float2 wA = *(const float2*)&wch[k*100 + toc*6];
            float2 wB = *(const float2*)&wch[k*100 + toc*6 + 2];
            float2 wC = *(const float2*)&wch[k*100 + toc*6 + 4];
            float xv[8];
            #pragma unroll
            for (int i = 0; i < 8; ++i) xv[i] = xch[k*128 + tp + 16*i];
            #pragma unroll
            for (int i = 0; i < 8; ++i) {
                acc[0][i] = fmaf(wA.x, xv[i], acc[0][i]);
                acc[1][i] = fmaf(wA.y, xv[i], acc[1][i]);
                acc[2][i] = fmaf(wB.x, xv[i], acc[2][i]);
                acc[3][i] = fmaf(wB.y, xv[i], acc[3][i]);
                acc[4][i] = fmaf(wC.x, xv[i], acc[4][i]);
                acc[5][i] = fmaf(wC.y, xv[i], acc[5][i]);
            }
        }
        if (kc == 224) break;
        __syncthreads();
        #pragma unroll
        for (int i = 0; i < 3; ++i) {
            wch[wdst[i]      ] = pwr[i].x; wch[wdst[i] + 100] = pwr[i].y;
            wch[wdst[i] + 200] = pwr[i].z; wch[wdst[i] + 300] = pwr[i].w;
        }
        #pragma unroll
        for (int i = 0; i < 4; ++i) *(float4*)&xch[xdst[i]] = pxr[i];
        __syncthreads();
        kc += 32;
    }

    // epilogue: p'' -> (bb, fold, n) -> out[bb][oc][w][h]
    const int fold0 = (pxbase >> 6) & 63;
    #pragma unroll
    for (int i = 0; i < 8; ++i) {
        int n    = 16*(i & 3) + tp;
        int fold = fold0 + (i >> 2);
        int f1 = fold >> 3, f2 = fold & 7;
        int r = n >> 3, hh = n & 7;
        size_t oaddr = (size_t)bb*96*4096 + (size_t)(toc*6)*4096
                     + (size_t)(f1*8 + r)*64 + f2*8 + hh;
        out[oaddr          ] = acc[0][i];
        out[oaddr +   4096 ] = acc[1][i];
        out[oaddr + 2*4096 ] = acc[2][i];
        out[oaddr + 3*4096 ] = acc[3][i];
        out[oaddr + 4*4096 ] = acc[4][i];
        out[oaddr + 5*4096 ] = acc[5][i];
    }
}

extern "C" void kernel_launch(void* const* d_in, const int* in_sizes, int n_in,
                              void* d_out, int out_size, void* d_ws, size_t ws_size,
                              hipStream_t stream) {
    (void)in_sizes; (void)n_in; (void)out_size; (void)ws_size;
    float* disp = (float*)d_ws;   // 256*65536 floats = 64 MiB, layout [ch][p'']
    cc_main<<<dim3(2048), dim3(TPB), 0, stream>>>(
        (const float*)d_in[0],  // x
        (const float*)d_in[1],  // Wf
        (const float*)d_in[2],  // bf
        (const float*)d_in[3],  // Wv
        (const float*)d_in[4],  // bv
        (const float*)d_in[7],  // sim_alpha
        (const float*)d_in[8],  // sim_beta
        disp);
    cc_proj<<<dim3(512), dim3(TPB), 0, stream>>>(
        disp,
        (const float*)d_in[5],  // Wp
        (const float*)d_in[6],  // bp
        (float*)d_out);
}

// Round 8
// 277.080 us; speedup vs baseline: 1.7493x; 1.1239x over previous
//
#include <hip/hip_runtime.h>
#include <math.h>

// ContextCluster, fp32, MI355X gfx950 — round 8.
// R7 + fix: cluster rg-loop fully unrolled so acc[8][8] indices are all
// compile-time constants (R7's `#pragma unroll 1` made acc scratch-allocated:
// VGPR 84 + 674 MB scratch WRITE). K2 XCD mapping = identity.
// K1: register-tiled GEMM conv (128ch x 128px, thread tile 8x8, K=96 in 3
//     chunks, register prefetch) + per-wave fused cluster, disp[ch][p''].
// K2: register-tiled GEMM proj C[96][p''] = Wp @ disp, thread tile 6x8.

#define TPB 256

__global__ __launch_bounds__(TPB, 2)
void cc_main(const float* __restrict__ x,
             const float* __restrict__ Wf, const float* __restrict__ bf,
             const float* __restrict__ Wv, const float* __restrict__ bv,
             const float* __restrict__ salpha, const float* __restrict__ sbeta,
             float* __restrict__ disp)
{
    // GEMM phase: Wt = smem[0..4096) [k][128ch], Xt = smem[4096..8192) [k][128px]
    // Cluster phase: fvbuf = smem[0..8320) [128ch][65]
    __shared__ __align__(16) float smem[8320];
    __shared__ float cfs[2][132], cvs[2][132], swb[2][256], aggs[2][132];

    const int t    = threadIdx.x;
    const int lane = t & 63;
    const int wid  = __builtin_amdgcn_readfirstlane(t >> 6);  // 0..3
    const int tc   = t >> 4;          // 0..15: ch-group (8 ch)
    const int tp   = t & 15;          // px-group (8 px, stride 16)
    const int blk  = blockIdx.x;
    const int heg  = blk >> 9;        // head-pair 0..3 (heads 2heg, 2heg+1)
    const int pxt  = blk & 511;       // px-tile; pxt%8 = XCD
    const int bb   = pxt >> 5;        // batch
    const int fp   = pxt & 31;        // fold-pair: folds 2fp, 2fp+1

    const float* xb = x + (size_t)bb*96*4096;

    // ---- accumulators, bias-init ----
    float acc[8][8];
    {
        const float* bsrc = (tc < 8) ? (bf + heg*64 + tc*8)
                                     : (bv + heg*64 + (tc-8)*8);
        float4 b0 = *(const float4*)bsrc;
        float4 b1 = *(const float4*)(bsrc + 4);
        #pragma unroll
        for (int i = 0; i < 8; ++i) {
            acc[0][i]=b0.x; acc[1][i]=b0.y; acc[2][i]=b0.z; acc[3][i]=b0.w;
            acc[4][i]=b1.x; acc[5][i]=b1.y; acc[6][i]=b1.z; acc[7][i]=b1.w;
        }
    }

    // ---- staging decode (t-constant) ----
    int xoff[4], xdst[4], wdst[4];
    const float* wptr[4];
    #pragma unroll
    for (int i = 0; i < 4; ++i) {
        int fl = i*256 + t;
        int kl = fl >> 5, sg = fl & 31;          // X: k-local, float4-col
        int region = sg >> 4, s4 = sg & 15;
        int fold = fp*2 + region;
        xoff[i] = kl*4096 + ((fold>>3)*8 + (s4>>1))*64 + (fold&7)*8 + (s4&1)*4;
        xdst[i] = 4096 + kl*128 + sg*4;
        int rr = fl >> 3, kq = fl & 7;           // W: ch-row, float4-k
        wptr[i] = ((rr < 64) ? (Wf + (size_t)(heg*64 + rr)*96)
                             : (Wv + (size_t)(heg*64 + rr - 64)*96)) + kq*4;
        wdst[i] = (kq*4)*128 + rr;
    }

    float4 pxr[4], pwr[4];
    #pragma unroll
    for (int i = 0; i < 4; ++i) {
        pxr[i] = *(const float4*)(xb + xoff[i]);
        pwr[i] = *(const float4*)(wptr[i]);
    }
    #pragma unroll
    for (int i = 0; i < 4; ++i) {
        *(float4*)&smem[xdst[i]] = pxr[i];
        smem[wdst[i]      ] = pwr[i].x;
        smem[wdst[i] + 128] = pwr[i].y;
        smem[wdst[i] + 256] = pwr[i].z;
        smem[wdst[i] + 384] = pwr[i].w;
    }
    __syncthreads();                  // chunk0 ready

    for (int kc = 0; ; ) {
        if (kc < 64) {                // prefetch next chunk into regs
            #pragma unroll
            for (int i = 0; i < 4; ++i) {
                pxr[i] = *(const float4*)(xb + (kc+32)*4096 + xoff[i]);
                pwr[i] = *(const float4*)(wptr[i] + kc + 32);
            }
        }
        // ---- GEMM on current chunk: 32 k, 64 FMA/thread/k ----
        #pragma unroll 4
        for (int k = 0; k < 32; ++k) {
            float4 wa  = *(const float4*)&smem[k*128 + tc*8];
            float4 wb4 = *(const float4*)&smem[k*128 + tc*8 + 4];
            float xv[8];
            #pragma unroll
            for (int i = 0; i < 8; ++i) xv[i] = smem[4096 + k*128 + tp + 16*i];
            #pragma unroll
            for (int i = 0; i < 8; ++i) {
                acc[0][i] = fmaf(wa.x,  xv[i], acc[0][i]);
                acc[1][i] = fmaf(wa.y,  xv[i], acc[1][i]);
                acc[2][i] = fmaf(wa.z,  xv[i], acc[2][i]);
                acc[3][i] = fmaf(wa.w,  xv[i], acc[3][i]);
                acc[4][i] = fmaf(wb4.x, xv[i], acc[4][i]);
                acc[5][i] = fmaf(wb4.y, xv[i], acc[5][i]);
                acc[6][i] = fmaf(wb4.z, xv[i], acc[6][i]);
                acc[7][i] = fmaf(wb4.w, xv[i], acc[7][i]);
            }
        }
        if (kc == 64) break;
        __syncthreads();              // chunk consumed
        #pragma unroll
        for (int i = 0; i < 4; ++i) {
            *(float4*)&smem[xdst[i]] = pxr[i];
            smem[wdst[i]      ] = pwr[i].x;
            smem[wdst[i] + 128] = pwr[i].y;
            smem[wdst[i] + 256] = pwr[i].z;
            smem[wdst[i] + 384] = pwr[i].w;
        }
        __syncthreads();              // next chunk ready
        kc += 32;
    }

    // ---- cluster: 2 region passes, FULLY UNROLLED (acc indices constant) ----
    const float alpha = salpha[0], beta = sbeta[0];
    #pragma unroll
    for (int rg = 0; rg < 2; ++rg) {
        __syncthreads();              // prior smem use done
        // dump region rg: fvbuf[ch][n] (stride 65)
        #pragma unroll
        for (int j = 0; j < 8; ++j)
            #pragma unroll
            for (int i2 = 0; i2 < 4; ++i2)
                smem[(tc*8 + j)*65 + tp + 16*i2] = acc[j][i2 + rg*4];
        __syncthreads();

        if ((wid >> 1) == rg) {
            const int he = wid & 1, slot = he;
            const int fold = fp*2 + rg;
            // pool: lane -> (m = lane>>4, c0 = (lane&15)*2), 2 centers each
            {
                int m = lane >> 4, c0 = (lane & 15)*2;
                int pw = m >> 1, ph = m & 1;
                #pragma unroll
                for (int cc = 0; cc < 2; ++cc) {
                    int c = c0 + cc;
                    float mf = -3.402823466e38f, mv = -3.402823466e38f;
                    #pragma unroll
                    for (int a = 0; a < 4; ++a)
                        #pragma unroll
                        for (int b2 = 0; b2 < 4; ++b2) {
                            int n = (pw*4 + a)*8 + ph*4 + b2;
                            mf = fmaxf(mf, smem[(he*32 + c)*65 + n]);
                            mv = fmaxf(mv, smem[(64 + he*32 + c)*65 + n]);
                        }
                    cfs[slot][m*33 + c] = mf;
                    cvs[slot][m*33 + c] = mv;
                }
            }
            // sims (lane = n)
            float d0=0,d1=0,d2=0,d3=0,pn=0,cn0=0,cn1=0,cn2=0,cn3=0;
            #pragma unroll 8
            for (int c = 0; c < 32; ++c) {
                float fv = smem[(he*32 + c)*65 + lane];
                float m0 = cfs[slot][c], m1 = cfs[slot][33+c];
                float m2 = cfs[slot][66+c], m3 = cfs[slot][99+c];
                d0 = fmaf(m0, fv, d0); d1 = fmaf(m1, fv, d1);
                d2 = fmaf(m2, fv, d2); d3 = fmaf(m3, fv, d3);
                pn = fmaf(fv, fv, pn);
                cn0 = fmaf(m0, m0, cn0); cn1 = fmaf(m1, m1, cn1);
                cn2 = fmaf(m2, m2, cn2); cn3 = fmaf(m3, m3, cn3);
            }
            float ip = 1.f / fmaxf(sqrtf(pn), 1e-12f);
            float z0 = beta + alpha*(d0*(1.f/fmaxf(sqrtf(cn0),1e-12f))*ip);
            float z1 = beta + alpha*(d1*(1.f/fmaxf(sqrtf(cn1),1e-12f))*ip);
            float z2 = beta + alpha*(d2*(1.f/fmaxf(sqrtf(cn2),1e-12f))*ip);
            float z3 = beta + alpha*(d3*(1.f/fmaxf(sqrtf(cn3),1e-12f))*ip);
            float s0 = 1.f/(1.f + expf(-z0));
            float s1 = 1.f/(1.f + expf(-z1));
            float s2 = 1.f/(1.f + expf(-z2));
            float s3 = 1.f/(1.f + expf(-z3));
            int bi = 0; float bvv = s0;        // first-max tie-break
            if (s1 > bvv) { bvv = s1; bi = 1; }
            if (s2 > bvv) { bvv = s2; bi = 2; }
            if (s3 > bvv) { bvv = s3; bi = 3; }
            int cnt0 = __popcll(__ballot(bi == 0));
            int cnt1 = __popcll(__ballot(bi == 1));
            int cnt2 = __popcll(__ballot(bi == 2));
            int cnt3 = __popcll(__ballot(bi == 3));
            swb[slot][lane]       = (bi==0) ? bvv : 0.f;
            swb[slot][64 + lane]  = (bi==1) ? bvv : 0.f;
            swb[slot][128 + lane] = (bi==2) ? bvv : 0.f;
            swb[slot][192 + lane] = (bi==3) ? bvv : 0.f;
            // agg
            #pragma unroll
            for (int it = 0; it < 2; ++it) {
                int m = it*2 + (lane >> 5);
                int c = lane & 31;
                float s = 0.f;
                #pragma unroll 8
                for (int n2 = 0; n2 < 64; ++n2)
                    s = fmaf(smem[(64 + he*32 + c)*65 + n2],
                             swb[slot][m*64 + n2], s);
                int cm = (m==0) ? cnt0 : (m==1) ? cnt1 : (m==2) ? cnt2 : cnt3;
                aggs[slot][m*33 + c] = (s + cvs[slot][m*33 + c]) / (float)(cm + 1);
            }
            // dispatch -> disp[ch][p'']
            const int e32 = (heg*2 + he)*32;
            const size_t obase = (size_t)bb*4096 + (size_t)fold*64 + lane;
            #pragma unroll 4
            for (int c = 0; c < 32; ++c)
                disp[(size_t)(e32 + c)*65536 + obase] = aggs[slot][bi*33 + c] * bvv;
        }
    }
}

// K2: C[96][p''] = Wp[96][256] @ disp[256][p''] + bp; thread tile 6oc x 8px.
__global__ __launch_bounds__(TPB, 3)
void cc_proj(const float* __restrict__ disp, const float* __restrict__ Wp,
             const float* __restrict__ bp, float* __restrict__ out)
{
    __shared__ __align__(16) float wch[3200];    // [32k][100] (oc, pad 100)
    __shared__ __align__(16) float xch[4096];    // [32k][128px]
    const int t   = threadIdx.x;
    const int toc = t >> 4;           // 0..15: oc-group (6 oc)
    const int tp  = t & 15;           // px-group (8 px, stride 16)
    const int pxt = blockIdx.x;       // identity: pxt%8 == K1 writer's blk%8
    const int pxbase = pxt * 128;
    const int bb = pxbase >> 12;

    float acc[6][8];
    {
        float b0 = bp[toc*6+0], b1 = bp[toc*6+1], b2 = bp[toc*6+2];
        float b3 = bp[toc*6+3], b4 = bp[toc*6+4], b5 = bp[toc*6+5];
        #pragma unroll
        for (int i = 0; i < 8; ++i) {
            acc[0][i]=b0; acc[1][i]=b1; acc[2][i]=b2;
            acc[3][i]=b3; acc[4][i]=b4; acc[5][i]=b5;
        }
    }

    // staging decode
    int woffg[3], wdst[3], xoffg[4], xdst[4];
    #pragma unroll
    for (int i = 0; i < 3; ++i) {
        int fl = i*256 + t;
        int oc2 = fl >> 3, kq = fl & 7;
        woffg[i] = oc2*256 + kq*4;
        wdst[i]  = (kq*4)*100 + oc2;
    }
    #pragma unroll
    for (int i = 0; i < 4; ++i) {
        int fl = i*256 + t;
        int kl = fl >> 5, sg = fl & 31;
        xoffg[i] = kl*65536 + pxbase + sg*4;
        xdst[i]  = kl*128 + sg*4;
    }

    float4 pwr[3], pxr[4];
    #pragma unroll
    for (int i = 0; i < 3; ++i) pwr[i] = *(const float4*)(Wp + woffg[i]);
    #pragma unroll
    for (int i = 0; i < 4; ++i) pxr[i] = *(const float4*)(disp + xoffg[i]);
    #pragma unroll
    for (int i = 0; i < 3; ++i) {
        wch[wdst[i]      ] = pwr[i].x; wch[wdst[i] + 100] = pwr[i].y;
        wch[wdst[i] + 200] = pwr[i].z; wch[wdst[i] + 300] = pwr[i].w;
    }
    #pragma unroll
    for (int i = 0; i < 4; ++i) *(float4*)&xch[xdst[i]] = pxr[i];
    __syncthreads();

    for (int kc = 0; ; ) {
        if (kc < 224) {
            #pragma unroll
            for (int i = 0; i < 3; ++i)
                pwr[i] = *(const float4*)(Wp + woffg[i] + kc + 32);
            #pragma unroll
            for (int i = 0; i < 4; ++i)
                pxr[i] = *(const float4*)(disp + xoffg[i] + (size_t)(kc+32)*65536);
        }
        #pragma unroll 4
        for (int k = 0; k < 32; ++k) {
            float2 wA = *(const float2*)&wch[k*100 + toc*6];
            float2 wB = *(const float2*)&wch[k*100 + toc*6 + 2];
            float2 wC = *(const float2*)&wch[k*100 + toc*6 + 4];
            float xv[8];
            #pragma unroll
            for (int i = 0; i < 8; ++i) xv[i] = xch[k*128 + tp + 16*i];
            #pragma unroll
            for (int i = 0; i < 8; ++i) {
                acc[0][i] = fmaf(wA.x, xv[i], acc[0][i]);
                acc[1][i] = fmaf(wA.y, xv[i], acc[1][i]);
                acc[2][i] = fmaf(wB.x, xv[i], acc[2][i]);
                acc[3][i] = fmaf(wB.y, xv[i], acc[3][i]);
                acc[4][i] = fmaf(wC.x, xv[i], acc[4][i]);
                acc[5][i] = fmaf(wC.y, xv[i], acc[5][i]);
            }
        }
        if (kc == 224) break;
        __syncthreads();
        #pragma unroll
        for (int i = 0; i < 3; ++i) {
            wch[wdst[i]      ] = pwr[i].x; wch[wdst[i] + 100] = pwr[i].y;
            wch[wdst[i] + 200] = pwr[i].z; wch[wdst[i] + 300] = pwr[i].w;
        }
        #pragma unroll
        for (int i = 0; i < 4; ++i) *(float4*)&xch[xdst[i]] = pxr[i];
        __syncthreads();
        kc += 32;
    }

    // epilogue: p'' -> (bb, fold, n) -> out[bb][oc][w][h]
    const int fold0 = (pxbase >> 6) & 63;
    #pragma unroll
    for (int i = 0; i < 8; ++i) {
        int n    = 16*(i & 3) + tp;
        int fold = fold0 + (i >> 2);
        int f1 = fold >> 3, f2 = fold & 7;
        int r = n >> 3, hh = n & 7;
        size_t oaddr = (size_t)bb*96*4096 + (size_t)(toc*6)*4096
                     + (size_t)(f1*8 + r)*64 + f2*8 + hh;
        out[oaddr          ] = acc[0][i];
        out[oaddr +   4096 ] = acc[1][i];
        out[oaddr + 2*4096 ] = acc[2][i];
        out[oaddr + 3*4096 ] = acc[3][i];
        out[oaddr + 4*4096 ] = acc[4][i];
        out[oaddr + 5*4096 ] = acc[5][i];
    }
}

extern "C" void kernel_launch(void* const* d_in, const int* in_sizes, int n_in,
                              void* d_out, int out_size, void* d_ws, size_t ws_size,
                              hipStream_t stream) {
    (void)in_sizes; (void)n_in; (void)out_size; (void)ws_size;
    float* disp = (float*)d_ws;   // 256*65536 floats = 64 MiB, layout [ch][p'']
    cc_main<<<dim3(2048), dim3(TPB), 0, stream>>>(
        (const float*)d_in[0],  // x
        (const float*)d_in[1],  // Wf
        (const float*)d_in[2],  // bf
        (const float*)d_in[3],  // Wv
        (const float*)d_in[4],  // bv
        (const float*)d_in[7],  // sim_alpha
        (const float*)d_in[8],  // sim_beta
        disp);
    cc_proj<<<dim3(512), dim3(TPB), 0, stream>>>(
        disp,
        (const float*)d_in[5],  // Wp
        (const float*)d_in[6],  // bp
        (float*)d_out);
}

// Round 9
// 266.764 us; speedup vs baseline: 1.8169x; 1.0387x over previous
//
#include <hip/hip_runtime.h>
#include <math.h>

// ContextCluster, fp32, MI355X gfx950 — round 9.
// R8 failures fixed: (a) 8x8 thread tile + prefetch spilled (VGPR 88, 54 MB
// scratch WRITE) -> tile now 8x4 (acc 32 regs); (b) W-transpose staging had
// 8-way LDS bank conflicts (7M cyc) -> decode rr=fl&127 gives 64 consecutive
// rr per store instr = 2-way = free; (c) occupancy 18.6% -> 33 KB LDS,
// 4 blocks/CU co-resident, 4096-block grid (16/CU queued).
// K1: conv GEMM 128ch x 64px (one fold), K=96, reg-prefetched chunks +
//     per-wave fused cluster -> disp[ch][p''], p''= bb*4096+fold*64+n.
// K2: proj GEMM 96oc x 64px, K=256, 1024 blocks, conflict-free W staging.

#define TPB 256

__global__ __launch_bounds__(TPB, 4)
void cc_main(const float* __restrict__ x,
             const float* __restrict__ Wf, const float* __restrict__ bf,
             const float* __restrict__ Wv, const float* __restrict__ bv,
             const float* __restrict__ salpha, const float* __restrict__ sbeta,
             float* __restrict__ disp)
{
    // GEMM: Wt = smem[0..4096) [32k][128ch], Xt = smem[4096..6144) [32k][64px]
    // Cluster: fvbuf = smem[0..8320) [128ch][65]
    __shared__ __align__(16) float smem[8320];
    __shared__ float cfs[2][132], cvs[2][132], swb[2][256], aggs[2][132];

    const int t    = threadIdx.x;
    const int lane = t & 63;
    const int wid  = __builtin_amdgcn_readfirstlane(t >> 6);  // 0..3
    const int tc   = t >> 4;          // 0..15: ch-group (8 ch)
    const int tp   = t & 15;          // px-group (4 px, stride 16)
    const int blk  = blockIdx.x;
    const int heg  = blk >> 10;       // head-pair 0..3
    const int bb   = (blk >> 6) & 15; // batch
    const int fold = blk & 63;        // region; blk%8 = fold%8 = XCD
    const int f1   = fold >> 3, f2 = fold & 7;

    const float* xb = x + (size_t)bb*96*4096 + (size_t)(f1*8)*64 + f2*8;

    // ---- accumulators (8 ch x 4 px), bias-init ----
    float acc[8][4];
    {
        const float* bsrc = (tc < 8) ? (bf + heg*64 + tc*8)
                                     : (bv + heg*64 + (tc-8)*8);
        float4 b0 = *(const float4*)bsrc;
        float4 b1 = *(const float4*)(bsrc + 4);
        #pragma unroll
        for (int i = 0; i < 4; ++i) {
            acc[0][i]=b0.x; acc[1][i]=b0.y; acc[2][i]=b0.z; acc[3][i]=b0.w;
            acc[4][i]=b1.x; acc[5][i]=b1.y; acc[6][i]=b1.z; acc[7][i]=b1.w;
        }
    }

    // ---- staging decode (t-constant) ----
    // X: 512 float4/chunk, 2/thread
    int xoff[2], xdst[2];
    #pragma unroll
    for (int i = 0; i < 2; ++i) {
        int fl = i*256 + t;
        int kl = fl >> 4, sg = fl & 15;
        xoff[i] = kl*4096 + (sg >> 1)*64 + (sg & 1)*4;
        xdst[i] = 4096 + kl*64 + sg*4;
    }
    // W: 1024 float4/chunk, 4/thread; rr = fl&127 -> 64 consecutive rr per
    // store instr -> 2 lanes/bank (conflict-free). kq wave-uniform.
    int wdst[4];
    const float* wptr[4];
    #pragma unroll
    for (int i = 0; i < 4; ++i) {
        int fl = i*256 + t;
        int rr = fl & 127, kq = fl >> 7;
        wptr[i] = ((rr < 64) ? (Wf + (size_t)(heg*64 + rr)*96)
                             : (Wv + (size_t)(heg*64 + rr - 64)*96)) + kq*4;
        wdst[i] = (kq*4)*128 + rr;
    }

    float4 pxr[2], pwr[4];
    #pragma unroll
    for (int i = 0; i < 2; ++i) pxr[i] = *(const float4*)(xb + xoff[i]);
    #pragma unroll
    for (int i = 0; i < 4; ++i) pwr[i] = *(const float4*)(wptr[i]);
    #pragma unroll
    for (int i = 0; i < 2; ++i) *(float4*)&smem[xdst[i]] = pxr[i];
    #pragma unroll
    for (int i = 0; i < 4; ++i) {
        smem[wdst[i]      ] = pwr[i].x;
        smem[wdst[i] + 128] = pwr[i].y;
        smem[wdst[i] + 256] = pwr[i].z;
        smem[wdst[i] + 384] = pwr[i].w;
    }
    __syncthreads();                  // chunk0 ready

    for (int kc = 0; ; ) {
        if (kc < 64) {                // prefetch next chunk into regs
            #pragma unroll
            for (int i = 0; i < 2; ++i)
                pxr[i] = *(const float4*)(xb + (kc+32)*4096 + xoff[i]);
            #pragma unroll
            for (int i = 0; i < 4; ++i)
                pwr[i] = *(const float4*)(wptr[i] + kc + 32);
        }
        // ---- GEMM chunk: 32 k, 32 FMA/thread/k ----
        #pragma unroll 4
        for (int k = 0; k < 32; ++k) {
            float4 wa  = *(const float4*)&smem[k*128 + tc*8];
            float4 wb4 = *(const float4*)&smem[k*128 + tc*8 + 4];
            float xv[4];
            #pragma unroll
            for (int i = 0; i < 4; ++i) xv[i] = smem[4096 + k*64 + tp + 16*i];
            #pragma unroll
            for (int i = 0; i < 4; ++i) {
                acc[0][i] = fmaf(wa.x,  xv[i], acc[0][i]);
                acc[1][i] = fmaf(wa.y,  xv[i], acc[1][i]);
                acc[2][i] = fmaf(wa.z,  xv[i], acc[2][i]);
                acc[3][i] = fmaf(wa.w,  xv[i], acc[3][i]);
                acc[4][i] = fmaf(wb4.x, xv[i], acc[4][i]);
                acc[5][i] = fmaf(wb4.y, xv[i], acc[5][i]);
                acc[6][i] = fmaf(wb4.z, xv[i], acc[6][i]);
                acc[7][i] = fmaf(wb4.w, xv[i], acc[7][i]);
            }
        }
        if (kc == 64) break;
        __syncthreads();              // chunk consumed
        #pragma unroll
        for (int i = 0; i < 2; ++i) *(float4*)&smem[xdst[i]] = pxr[i];
        #pragma unroll
        for (int i = 0; i < 4; ++i) {
            smem[wdst[i]      ] = pwr[i].x;
            smem[wdst[i] + 128] = pwr[i].y;
            smem[wdst[i] + 256] = pwr[i].z;
            smem[wdst[i] + 384] = pwr[i].w;
        }
        __syncthreads();              // next chunk ready
        kc += 32;
    }

    // ---- cluster: dump conv result, waves 0/1 handle heads he=wid ----
    const float alpha = salpha[0], beta = sbeta[0];
    __syncthreads();                  // GEMM reads of smem done
    #pragma unroll
    for (int j = 0; j < 8; ++j)
        #pragma unroll
        for (int i2 = 0; i2 < 4; ++i2)
            smem[(tc*8 + j)*65 + tp + 16*i2] = acc[j][i2];
    __syncthreads();

    if (wid < 2) {
        const int he = wid, slot = he;
        // pool: lane -> (m = lane>>4, c0 = (lane&15)*2), 2 centers each
        {
            int m = lane >> 4, c0 = (lane & 15)*2;
            int pw = m >> 1, ph = m & 1;
            #pragma unroll
            for (int cc = 0; cc < 2; ++cc) {
                int c = c0 + cc;
                float mf = -3.402823466e38f, mv = -3.402823466e38f;
                #pragma unroll
                for (int a = 0; a < 4; ++a)
                    #pragma unroll
                    for (int b2 = 0; b2 < 4; ++b2) {
                        int n = (pw*4 + a)*8 + ph*4 + b2;
                        mf = fmaxf(mf, smem[(he*32 + c)*65 + n]);
                        mv = fmaxf(mv, smem[(64 + he*32 + c)*65 + n]);
                    }
                cfs[slot][m*33 + c] = mf;
                cvs[slot][m*33 + c] = mv;
            }
        }
        // sims (lane = n)
        float d0=0,d1=0,d2=0,d3=0,pn=0,cn0=0,cn1=0,cn2=0,cn3=0;
        #pragma unroll 8
        for (int c = 0; c < 32; ++c) {
            float fv = smem[(he*32 + c)*65 + lane];
            float m0 = cfs[slot][c], m1 = cfs[slot][33+c];
            float m2 = cfs[slot][66+c], m3 = cfs[slot][99+c];
            d0 = fmaf(m0, fv, d0); d1 = fmaf(m1, fv, d1);
            d2 = fmaf(m2, fv, d2); d3 = fmaf(m3, fv, d3);
            pn = fmaf(fv, fv, pn);
            cn0 = fmaf(m0, m0, cn0); cn1 = fmaf(m1, m1, cn1);
            cn2 = fmaf(m2, m2, cn2); cn3 = fmaf(m3, m3, cn3);
        }
        float ip = 1.f / fmaxf(sqrtf(pn), 1e-12f);
        float z0 = beta + alpha*(d0*(1.f/fmaxf(sqrtf(cn0),1e-12f))*ip);
        float z1 = beta + alpha*(d1*(1.f/fmaxf(sqrtf(cn1),1e-12f))*ip);
        float z2 = beta + alpha*(d2*(1.f/fmaxf(sqrtf(cn2),1e-12f))*ip);
        float z3 = beta + alpha*(d3*(1.f/fmaxf(sqrtf(cn3),1e-12f))*ip);
        float s0 = 1.f/(1.f + expf(-z0));
        float s1 = 1.f/(1.f + expf(-z1));
        float s2 = 1.f/(1.f + expf(-z2));
        float s3 = 1.f/(1.f + expf(-z3));
        int bi = 0; float bvv = s0;   // first-max tie-break
        if (s1 > bvv) { bvv = s1; bi = 1; }
        if (s2 > bvv) { bvv = s2; bi = 2; }
        if (s3 > bvv) { bvv = s3; bi = 3; }
        int cnt0 = __popcll(__ballot(bi == 0));
        int cnt1 = __popcll(__ballot(bi == 1));
        int cnt2 = __popcll(__ballot(bi == 2));
        int cnt3 = __popcll(__ballot(bi == 3));
        swb[slot][lane]       = (bi==0) ? bvv : 0.f;
        swb[slot][64 + lane]  = (bi==1) ? bvv : 0.f;
        swb[slot][128 + lane] = (bi==2) ? bvv : 0.f;
        swb[slot][192 + lane] = (bi==3) ? bvv : 0.f;
        // agg: 2 iters, lane -> (m = it*2 + lane>>5, c = lane&31)
        #pragma unroll
        for (int it = 0; it < 2; ++it) {
            int m = it*2 + (lane >> 5);
            int c = lane & 31;
            float s = 0.f;
            #pragma unroll 8
            for (int n2 = 0; n2 < 64; ++n2)
                s = fmaf(smem[(64 + he*32 + c)*65 + n2],
                         swb[slot][m*64 + n2], s);
            int cm = (m==0) ? cnt0 : (m==1) ? cnt1 : (m==2) ? cnt2 : cnt3;
            aggs[slot][m*33 + c] = (s + cvs[slot][m*33 + c]) / (float)(cm + 1);
        }
        // dispatch -> disp[ch][p'']
        const int e32 = (heg*2 + he)*32;
        const size_t obase = (size_t)bb*4096 + (size_t)fold*64 + lane;
        #pragma unroll 4
        for (int c = 0; c < 32; ++c)
            disp[(size_t)(e32 + c)*65536 + obase] = aggs[slot][bi*33 + c] * bvv;
    }
}

// K2: C[96][p''] = Wp[96][256] @ disp[256][p''] + bp; tile 96oc x 64px,
// thread tile 6oc x 4px, 1024 blocks (4/CU), conflict-free W staging.
__global__ __launch_bounds__(TPB, 4)
void cc_proj(const float* __restrict__ disp, const float* __restrict__ Wp,
             const float* __restrict__ bp, float* __restrict__ out)
{
    __shared__ __align__(16) float wch[3200];    // [32k][100] (oc, pad 100)
    __shared__ __align__(16) float xch[2048];    // [32k][64px]
    const int t   = threadIdx.x;
    const int toc = t >> 4;           // 0..15: oc-group (6 oc)
    const int tp  = t & 15;           // px-group (4 px, stride 16)
    const int pxt = blockIdx.x;       // pxt%8 = fold%8 = K1 writer's XCD
    const int pxbase = pxt * 64;
    const int bb   = pxt >> 6;
    const int fold = pxt & 63;
    const int f1 = fold >> 3, f2 = fold & 7;

    float acc[6][4];
    {
        float b0 = bp[toc*6+0], b1 = bp[toc*6+1], b2 = bp[toc*6+2];
        float b3 = bp[toc*6+3], b4 = bp[toc*6+4], b5 = bp[toc*6+5];
        #pragma unroll
        for (int i = 0; i < 4; ++i) {
            acc[0][i]=b0; acc[1][i]=b1; acc[2][i]=b2;
            acc[3][i]=b3; acc[4][i]=b4; acc[5][i]=b5;
        }
    }

    // staging decode. W: 768 float4/chunk, 3/thread; oc consecutive per
    // store instr -> ~2-way banks (free). X: 512 float4/chunk, 2/thread.
    int woffg[3], wdst[3], xoffg[2], xdst[2];
    #pragma unroll
    for (int i = 0; i < 3; ++i) {
        int fl = i*256 + t;           // 0..767
        int oc2 = fl % 96, kq = fl / 96;
        woffg[i] = oc2*256 + kq*4;
        wdst[i]  = (kq*4)*100 + oc2;
    }
    #pragma unroll
    for (int i = 0; i < 2; ++i) {
        int fl = i*256 + t;
        int kl = fl >> 4, sg = fl & 15;
        xoffg[i] = kl*65536 + pxbase + sg*4;
        xdst[i]  = kl*64 + sg*4;
    }

    float4 pwr[3], pxr[2];
    #pragma unroll
    for (int i = 0; i < 3; ++i) pwr[i] = *(const float4*)(Wp + woffg[i]);
    #pragma unroll
    for (int i = 0; i < 2; ++i) pxr[i] = *(const float4*)(disp + xoffg[i]);
    #pragma unroll
    for (int i = 0; i < 3; ++i) {
        wch[wdst[i]      ] = pwr[i].x; wch[wdst[i] + 100] = pwr[i].y;
        wch[wdst[i] + 200] = pwr[i].z; wch[wdst[i] + 300] = pwr[i].w;
    }
    #pragma unroll
    for (int i = 0; i < 2; ++i) *(float4*)&xch[xdst[i]] = pxr[i];
    __syncthreads();

    for (int kc = 0; ; ) {
        if (kc < 224) {
            #pragma unroll
            for (int i = 0; i < 3; ++i)
                pwr[i] = *(const float4*)(Wp + woffg[i] + kc + 32);
            #pragma unroll
            for (int i = 0; i < 2; ++i)
                pxr[i] = *(const float4*)(disp + xoffg[i] + (size_t)(kc+32)*65536);
        }
        #pragma unroll 4
        for (int k = 0; k < 32; ++k) {
            float2 wA = *(const float2*)&wch[k*100 + toc*6];
            float2 wB = *(const float2*)&wch[k*100 + toc*6 + 2];
            float2 wC = *(const float2*)&wch[k*100 + toc*6 + 4];
            float xv[4];
            #pragma unroll
            for (int i = 0; i < 4; ++i) xv[i] = xch[k*64 + tp + 16*i];
            #pragma unroll
            for (int i = 0; i < 4; ++i) {
                acc[0][i] = fmaf(wA.x, xv[i], acc[0][i]);
                acc[1][i] = fmaf(wA.y, xv[i], acc[1][i]);
                acc[2][i] = fmaf(wB.x, xv[i], acc[2][i]);
                acc[3][i] = fmaf(wB.y, xv[i], acc[3][i]);
                acc[4][i] = fmaf(wC.x, xv[i], acc[4][i]);
                acc[5][i] = fmaf(wC.y, xv[i], acc[5][i]);
            }
        }
        if (kc == 224) break;
        __syncthreads();
        #pragma unroll
        for (int i = 0; i < 3; ++i) {
            wch[wdst[i]      ] = pwr[i].x; wch[wdst[i] + 100] = pwr[i].y;
            wch[wdst[i] + 200] = pwr[i].z; wch[wdst[i] + 300] = pwr[i].w;
        }
        #pragma unroll
        for (int i = 0; i < 2; ++i) *(float4*)&xch[xdst[i]] = pxr[i];
        __syncthreads();
        kc += 32;
    }

    // epilogue: n = tp + 16*i -> out[bb][oc][f1*8 + n/8][f2*8 + n%8]
    #pragma unroll
    for (int i = 0; i < 4; ++i) {
        int n = tp + 16*i;
        int r = n >> 3, hh = n & 7;
        size_t oaddr = (size_t)bb*96*4096 + (size_t)(toc*6)*4096
                     + (size_t)(f1*8 + r)*64 + f2*8 + hh;
        out[oaddr          ] = acc[0][i];
        out[oaddr +   4096 ] = acc[1][i];
        out[oaddr + 2*4096 ] = acc[2][i];
        out[oaddr + 3*4096 ] = acc[3][i];
        out[oaddr + 4*4096 ] = acc[4][i];
        out[oaddr + 5*4096 ] = acc[5][i];
    }
}

extern "C" void kernel_launch(void* const* d_in, const int* in_sizes, int n_in,
                              void* d_out, int out_size, void* d_ws, size_t ws_size,
                              hipStream_t stream) {
    (void)in_sizes; (void)n_in; (void)out_size; (void)ws_size;
    float* disp = (float*)d_ws;   // 256*65536 floats = 64 MiB, layout [ch][p'']
    cc_main<<<dim3(4096), dim3(TPB), 0, stream>>>(
        (const float*)d_in[0],  // x
        (const float*)d_in[1],  // Wf
        (const float*)d_in[2],  // bf
        (const float*)d_in[3],  // Wv
        (const float*)d_in[4],  // bv
        (const float*)d_in[7],  // sim_alpha
        (const float*)d_in[8],  // sim_beta
        disp);
    cc_proj<<<dim3(1024), dim3(TPB), 0, stream>>>(
        disp,
        (const float*)d_in[5],  // Wp
        (const float*)d_in[6],  // bp
        (float*)d_out);
}